// Round 9
// baseline (228.318 us; speedup 1.0000x reference)
//
#include <hip/hip_runtime.h>
#include <cstdint>
#include <cstddef>

// ---------------------------------------------------------------------------
// MHA forward, bf16 MFMA pipeline, masked-key compaction.
// B=2, S=2048, D=1024, H=16, dk=64. mask is per (batch,key): ~50% of keys are
// dead for ALL heads/queries -> compact K/V to valid keys; attn iterates only
// ceil(cnt/128)*2 tiles (~18 vs 32).
//   0) scan:   per-batch prefix over mask -> pref[], cnt[]; compacted additive
//              mask (log2 domain); zero kh/vhT pad rows/cols (NaN guard)
//   1) prep:   cast q,k,v,W* fp32->bf16
//   2) proj3:  128x128 tiles, 768 blocks = 3/CU; kh/vhT stores compacted
//   3) attn:   R6 skeleton + compaction, P->PV via the R0/R10-PROVEN per-wave
//              LDS round-trip (NO inline asm anywhere -- isolates the R12
//              failure to the permlane path under runtime-loop codegen).
//   4) oproj:  64x128 tiles (2 blocks/CU), out = ao@Wo^T + bo (fp32)
// ---------------------------------------------------------------------------

using bf16   = __bf16;
using bf16x4 = __attribute__((ext_vector_type(4))) __bf16;
using bf16x8 = __attribute__((ext_vector_type(8))) __bf16;
using f32x4  = __attribute__((ext_vector_type(4))) float;

#define MFMA_BF16(a, b, c) __builtin_amdgcn_mfma_f32_16x16x32_bf16((a), (b), (c), 0, 0, 0)

__device__ __forceinline__ void gload_lds16(const void* g, void* l) {
  __builtin_amdgcn_global_load_lds((__attribute__((address_space(1))) void*)g,
                                   (__attribute__((address_space(3))) void*)l,
                                   16, 0, 0);
}

#define LOG2E 1.4426950408889634f

// ---------------------------------------------------------------------------
// 0) scan: one block per batch. Block-scan mask -> pref (compacted slot or -1),
//    cnt; compacted additive mask; zero kh/vhT pad region [cnt, nt2*64).
// ---------------------------------------------------------------------------
__global__ __launch_bounds__(256) void scan_kernel(
    const int* __restrict__ mask,   // [2][2048]
    int* __restrict__ pref,         // [4096]: dest slot or -1
    int* __restrict__ cnt,          // [2]
    float* __restrict__ maskc,      // [2][2048] additive, log2 domain
    bf16* __restrict__ kh,          // zero pad rows
    bf16* __restrict__ vhT)         // zero pad cols
{
  const int b = blockIdx.x;
  const int tid = threadIdx.x;
  __shared__ int sums[256];

  const int base = b * 2048 + tid * 8;
  int v[8]; int s_ = 0;
#pragma unroll
  for (int j = 0; j < 8; ++j) { v[j] = (mask[base + j] != 0) ? 1 : 0; s_ += v[j]; }
  sums[tid] = s_;
  __syncthreads();
  for (int off = 1; off < 256; off <<= 1) {
    int x = sums[tid];
    int y = (tid >= off) ? sums[tid - off] : 0;
    __syncthreads();
    sums[tid] = x + y;
    __syncthreads();
  }
  const int excl  = tid ? sums[tid - 1] : 0;
  const int total = sums[255];
  int run = excl;
#pragma unroll
  for (int j = 0; j < 8; ++j) { pref[base + j] = v[j] ? run : -1; run += v[j]; }
  if (tid == 0) cnt[b] = total;

  int nt2 = ((total + 127) >> 7) * 2;
  if (nt2 < 2) nt2 = 2;
  const int span = nt2 * 64;                 // multiple of 128, <= 2048

  // compacted additive mask: 0 for valid slots, -inf (log2) for the rest
  for (int sc = tid; sc < 2048; sc += 256)
    maskc[b * 2048 + sc] = (sc < total) ? 0.0f : -1e9f * LOG2E;

  // zero kh pad rows [total, span): 16 heads x <=128 rows x 64 d
  for (int idx = tid; idx < 16 * 128; idx += 256) {
    const int h = idx >> 7, ro = idx & 127;
    const int s = total + ro;
    if (s < span) {
      bf16* p = kh + (((size_t)(b * 16 + h) * 2048 + s) * 64);
#pragma unroll
      for (int d = 0; d < 64; d += 8)
        *(bf16x8*)(p + d) = bf16x8{(bf16)0.f,(bf16)0.f,(bf16)0.f,(bf16)0.f,
                                   (bf16)0.f,(bf16)0.f,(bf16)0.f,(bf16)0.f};
    }
  }
  // zero vhT pad cols [total, span): 16 heads x 64 d-rows x <=128 cols
  for (int j = tid; j < 16 * 64 * 128; j += 256) {
    const int h = j >> 13, rem = j & 8191;
    const int d = rem >> 7, co = rem & 127;
    const int c = total + co;
    if (c < span)
      vhT[(((size_t)(b * 16 + h) * 64 + d) * 2048) + c] = (bf16)0.f;
  }
}

// ---------------------------------------------------------------------------
// 1) prep — 2 elements per thread, grid 8192 (exactly 3*NQ+4*NW float4s)
// ---------------------------------------------------------------------------
__global__ __launch_bounds__(256) void prep_kernel(
    const float* __restrict__ q, const float* __restrict__ k, const float* __restrict__ v,
    const float* __restrict__ Wq, const float* __restrict__ Wk,
    const float* __restrict__ Wv, const float* __restrict__ Wo,
    bf16* __restrict__ qb, bf16* __restrict__ kb, bf16* __restrict__ vb,
    bf16* __restrict__ Wqb, bf16* __restrict__ Wkb, bf16* __restrict__ Wvb,
    bf16* __restrict__ Wob)
{
  const int NQ = 1048576;
  const int NW = 262144;
  const int STRIDE = 8192 * 256;
#pragma unroll
  for (int s = 0; s < 2; ++s) {
    int i = blockIdx.x * 256 + threadIdx.x + s * STRIDE;
    if (i < 3 * NQ) {
      const float* src; bf16* dst; int j;
      if (i < NQ)        { src = q; dst = qb; j = i; }
      else if (i < 2*NQ) { src = k; dst = kb; j = i - NQ; }
      else               { src = v; dst = vb; j = i - 2*NQ; }
      float4 f = ((const float4*)src)[j];
      ((bf16x4*)dst)[j] = bf16x4{(bf16)f.x, (bf16)f.y, (bf16)f.z, (bf16)f.w};
    } else {
      int j = i - 3*NQ;
      const float* src; bf16* dst;
      if (j < NW)        { src = Wq; dst = Wqb; }
      else if (j < 2*NW) { src = Wk; dst = Wkb; j -= NW; }
      else if (j < 3*NW) { src = Wv; dst = Wvb; j -= 2*NW; }
      else               { src = Wo; dst = Wob; j -= 3*NW; }
      float4 f = ((const float4*)src)[j];
      ((bf16x4*)dst)[j] = bf16x4{(bf16)f.x, (bf16)f.y, (bf16)f.z, (bf16)f.w};
    }
  }
}

// ---------------------------------------------------------------------------
// 2) fused QKV projections, 128x128 tiles, grid 768 = 3 blocks/CU exactly.
//    kh rows and vhT cols stored at compacted slot pref[token] (skip masked).
// ---------------------------------------------------------------------------
__global__ __launch_bounds__(256, 3) void proj3_kernel(
    const bf16* __restrict__ Xq, const bf16* __restrict__ Xk, const bf16* __restrict__ Xv,
    const bf16* __restrict__ Wqb, const bf16* __restrict__ Wkb, const bf16* __restrict__ Wvb,
    const float* __restrict__ bq, const float* __restrict__ bk, const float* __restrict__ bv,
    const int* __restrict__ pref,
    bf16* __restrict__ qh, bf16* __restrict__ kh, bf16* __restrict__ vhT)
{
  __shared__ bf16 As[128 * 64];   // 16 KB
  __shared__ bf16 Bs[128 * 64];   // 16 KB

  const int bid = blockIdx.x;
  const int z   = bid >> 8;        // 0,1,2
  const int r_  = bid & 255;

  const int tid = threadIdx.x, w = tid >> 6, lane = tid & 63;
  const int wr = w >> 1, wc = w & 1;
  const int quad = lane >> 4, l16 = lane & 15;
  const int sw = l16 & 7;
  const int srow8 = lane >> 3;
  const int scol  = ((lane & 7) ^ srow8) * 8;

  const bf16* Aptr; const bf16* Bptr;
  int m0, n0;
  if (z == 2) { Aptr = Wvb; Bptr = Xv; m0 = (r_ >> 5) * 128; n0 = (r_ & 31) * 128; }
  else        { Aptr = (z == 0) ? Xq : Xk; Bptr = (z == 0) ? Wqb : Wkb;
                m0 = (r_ >> 3) * 128; n0 = (r_ & 7) * 128; }

  f32x4 acc[4][4];
#pragma unroll
  for (int mt = 0; mt < 4; ++mt)
#pragma unroll
    for (int nt = 0; nt < 4; ++nt)
      acc[mt][nt] = f32x4{0.f, 0.f, 0.f, 0.f};

  for (int k0 = 0; k0 < 1024; k0 += 64) {
#pragma unroll
    for (int c8 = 0; c8 < 8; ++c8) {
      const int c = w * 8 + c8;
      if (c < 16) {
        const int row = c * 8 + srow8;
        gload_lds16(Aptr + (size_t)(m0 + row) * 1024 + k0 + scol, As + c * 512);
      } else {
        const int cB = c - 16;
        const int row = cB * 8 + srow8;
        gload_lds16(Bptr + (size_t)(n0 + row) * 1024 + k0 + scol, Bs + cB * 512);
      }
    }
    __syncthreads();
#pragma unroll
    for (int kk = 0; kk < 2; ++kk) {
      bf16x8 af[4], bf[4];
#pragma unroll
      for (int mt = 0; mt < 4; ++mt)
        af[mt] = *(const bf16x8*)(As + (wr*64 + mt*16 + l16) * 64 + ((kk*4 + quad) ^ sw) * 8);
#pragma unroll
      for (int nt = 0; nt < 4; ++nt)
        bf[nt] = *(const bf16x8*)(Bs + (wc*64 + nt*16 + l16) * 64 + ((kk*4 + quad) ^ sw) * 8);
#pragma unroll
      for (int mt = 0; mt < 4; ++mt)
#pragma unroll
        for (int nt = 0; nt < 4; ++nt)
          acc[mt][nt] = MFMA_BF16(af[mt], bf[nt], acc[mt][nt]);
    }
    __syncthreads();
  }

  if (z == 2) {
    // C rows = Wv-row dv, cols = token; store vhT[bh][d][sc] compacted
    int sc4[4];
#pragma unroll
    for (int nt = 0; nt < 4; ++nt)
      sc4[nt] = pref[n0 + wc*64 + nt*16 + l16];
#pragma unroll
    for (int mt = 0; mt < 4; ++mt) {
      const int dvb = m0 + wr*64 + mt*16 + quad*4;
      const float4 bv4 = *(const float4*)(bv + dvb);
#pragma unroll
      for (int nt = 0; nt < 4; ++nt) {
        const int tok = n0 + wc*64 + nt*16 + l16;
        const int bb = tok >> 11;
        if (sc4[nt] >= 0) {
#pragma unroll
          for (int r = 0; r < 4; ++r) {
            const int dv = dvb + r;
            const int h = dv >> 6, d = dv & 63;
            vhT[(((size_t)bb*16 + h)*64 + d)*2048 + sc4[nt]] = (bf16)(acc[mt][nt][r] + (&bv4.x)[r]);
          }
        }
      }
    }
  } else if (z == 0) {
#pragma unroll
    for (int mt = 0; mt < 4; ++mt) {
#pragma unroll
      for (int nt = 0; nt < 4; ++nt) {
        const int n = n0 + wc*64 + nt*16 + l16;
        const int h = n >> 6, d = n & 63;
        const float bn = bq[n];
#pragma unroll
        for (int r = 0; r < 4; ++r) {
          const int m  = m0 + wr*64 + mt*16 + quad*4 + r;
          const int bb = m >> 11, s = m & 2047;
          const float val = acc[mt][nt][r] + bn;
          qh[(((size_t)bb*16 + h)*2048 + s)*64 + d] = (bf16)(val * (0.125f * LOG2E));
        }
      }
    }
  } else {
#pragma unroll
    for (int mt = 0; mt < 4; ++mt) {
      int dst4[4];
#pragma unroll
      for (int r = 0; r < 4; ++r)
        dst4[r] = pref[m0 + wr*64 + mt*16 + quad*4 + r];
#pragma unroll
      for (int nt = 0; nt < 4; ++nt) {
        const int n = n0 + wc*64 + nt*16 + l16;
        const int h = n >> 6, d = n & 63;
        const float bn = bk[n];
#pragma unroll
        for (int r = 0; r < 4; ++r) {
          const int m  = m0 + wr*64 + mt*16 + quad*4 + r;
          const int bb = m >> 11;
          if (dst4[r] >= 0) {
            const float val = acc[mt][nt][r] + bn;
            kh[(((size_t)bb*16 + h)*2048 + dst4[r])*64 + d] = (bf16)val;
          }
        }
      }
    }
  }
}

// ---------------------------------------------------------------------------
// 3) flash attention (R6 skeleton + compaction, LDS P round-trip): 256-thr
// blocks (4 waves, 128 q-rows), grid 512 = 2 blocks/CU; triple-buffered K/V
// LDS; K-fragments register-prefetched one tile ahead; P->PV via per-wave
// LDS staging (R0/R10-proven, no inline asm). Dynamic EVEN tile count
// nt2 = 2*ceil(cnt[b]/128). 1 barrier/tile. bh=(L&7)+8*(L>>7).
// ---------------------------------------------------------------------------
#define PSTRIDE 72   // P staging row stride (64+8): banks rotate, 16B aligned

#define ATTN_BODY(T, FKC, FKN, MKC, MKN)                                        \
  {                                                                             \
    if ((T) + 2 < nt2) stageTo((T) + 2, kvnn);                                  \
    if ((T) + 1 < nt2) {                                                        \
      _Pragma("unroll")                                                         \
      for (int mb = 0; mb < 4; ++mb)                                            \
        MKN[mb] = *(const float4*)(mbase + ((T) + 1) * 64 + mb * 16);           \
      const char* pA = kvb + kvnxt + laneA;                                     \
      const char* pB = kvb + kvnxt + laneB;                                     \
      _Pragma("unroll")                                                         \
      for (int mb = 0; mb < 4; ++mb) {                                          \
        FKN[mb*2+0] = *(const bf16x8*)(pA + mb*2048);                           \
        FKN[mb*2+1] = *(const bf16x8*)(pB + mb*2048);                           \
      }                                                                         \
    }                                                                           \
    bf16x8 fV[8];                                                               \
    {                                                                           \
      const char* pA = kvb + kvcur + 8192 + laneA;                              \
      const char* pB = kvb + kvcur + 8192 + laneB;                              \
      _Pragma("unroll")                                                         \
      for (int mb = 0; mb < 4; ++mb) {                                          \
        fV[mb*2+0] = *(const bf16x8*)(pA + mb*2048);                            \
        fV[mb*2+1] = *(const bf16x8*)(pB + mb*2048);                            \
      }                                                                         \
    }                                                                           \
    _Pragma("unroll")                                                           \
    for (int rb = 0; rb < 2; ++rb) {                                            \
      f32x4 sac[4];                                                             \
      _Pragma("unroll")                                                         \
      for (int mb = 0; mb < 4; ++mb)                                            \
        sac[mb] = f32x4{MKC[mb].x, MKC[mb].y, MKC[mb].z, MKC[mb].w};            \
      _Pragma("unroll")                                                         \
      for (int kk = 0; kk < 2; ++kk)                                            \
        _Pragma("unroll")                                                       \
        for (int mb = 0; mb < 4; ++mb)                                          \
          sac[mb] = MFMA_BF16(FKC[mb*2+kk], aQ[rb][kk], sac[mb]);               \
      float p[4][4];                                                            \
      _Pragma("unroll")                                                         \
      for (int mb = 0; mb < 4; ++mb) {                                          \
        _Pragma("unroll")                                                       \
        for (int r = 0; r < 4; ++r) p[mb][r] = __builtin_amdgcn_exp2f(sac[mb][r]); \
        lacc[rb] += f32x4{p[mb][0], p[mb][1], p[mb][2], p[mb][3]};              \
      }                                                                         \
      _Pragma("unroll")                                                         \
      for (int mb = 0; mb < 4; ++mb) {                                          \
        bf16x4 pk = bf16x4{(bf16)p[mb][0], (bf16)p[mb][1],                      \
                           (bf16)p[mb][2], (bf16)p[mb][3]};                     \
        *(bf16x4*)(bW + mb*16) = pk;                                            \
      }                                                                         \
      _Pragma("unroll")                                                         \
      for (int kk = 0; kk < 2; ++kk) {                                          \
        bf16x8 aP = *(const bf16x8*)(bR + kk*32);                               \
        _Pragma("unroll")                                                       \
        for (int mb = 0; mb < 4; ++mb)                                          \
          Oacc[rb][mb] = MFMA_BF16(fV[mb*2+kk], aP, Oacc[rb][mb]);              \
      }                                                                         \
    }                                                                           \
    __syncthreads();                                                            \
    { int tmp_ = kvcur; kvcur = kvnxt; kvnxt = kvnn; kvnn = tmp_; }             \
  }

__global__ __launch_bounds__(256, 2) void attn_kernel(
    const bf16* __restrict__ qh, const bf16* __restrict__ kh,
    const bf16* __restrict__ vhT, const float* __restrict__ maskc,
    const int* __restrict__ cnt, bf16* __restrict__ out)
{
  __shared__ bf16 KV[3][2][4096];       // [buf][K|V][64*64], 48 KB, XOR-swz
  __shared__ bf16 Ps[4][16 * PSTRIDE];  // per-wave P staging, 9 KB

  const int tid = threadIdx.x, w = tid >> 6, lane = tid & 63;
  const int quad = lane >> 4, l16 = lane & 15;
  const int sw = l16 & 7;
  const int srow8 = lane >> 3;
  const int scol  = ((lane & 7) ^ srow8) * 8;

  const int L  = blockIdx.x;
  const int bh = (L & 7) + ((L >> 7) << 3);
  const int qt = (L >> 3) & 15;
  const int b  = bh >> 4, h = bh & 15;
  const int q0 = qt * 128 + w * 32;

  const bf16* kbase = kh  + (size_t)bh * 2048 * 64;
  const bf16* vbase = vhT + (size_t)bh * 64 * 2048;
  const bf16* qbase = qh  + ((size_t)bh * 2048 + q0) * 64;
  const float* mbase = maskc + (size_t)b * 2048 + quad * 4;

  // dynamic even tile count from compacted key count
  const int total = cnt[b];
  int nt2 = ((total + 127) >> 7) * 2;
  if (nt2 < 2) nt2 = 2;

  char* kvb = (char*)&KV[0][0][0];
  bf16* Pw = Ps[w];

  auto stageTo = [&](int t, int bufoff) {
    const int kt0 = t * 64;
#pragma unroll
    for (int c2 = 0; c2 < 2; ++c2) {
      const int c   = w * 2 + c2;        // chunk 0..7, 1KB each
      const int row = c * 8 + srow8;
      gload_lds16(kbase + (size_t)(kt0 + row) * 64 + scol, kvb + bufoff + c * 1024);
      gload_lds16(vbase + (size_t)row * 2048 + kt0 + scol, kvb + bufoff + 8192 + c * 1024);
    }
  };

  // Q fragments (B-operand for S^T = K.Q^T)
  bf16x8 aQ[2][2];
#pragma unroll
  for (int rb = 0; rb < 2; ++rb)
#pragma unroll
    for (int kk = 0; kk < 2; ++kk)
      aQ[rb][kk] = *(const bf16x8*)(qbase + (size_t)(rb*16 + l16)*64 + kk*32 + quad*8);

  // loop-invariant LDS addressing (all ds ops get immediate offsets)
  const int laneA = l16 * 128 + ((quad    ) ^ sw) * 16;   // kk=0 slot
  const int laneB = l16 * 128 + ((quad + 4) ^ sw) * 16;   // kk=1 slot
  bf16*       bW = Pw + l16 * PSTRIDE + quad * 4;
  const bf16* bR = Pw + l16 * PSTRIDE + quad * 8;

  f32x4 Oacc[2][4];            // O^T: row d = mb*16+quad*4+r, col q = l16
  f32x4 lacc[2];               // vectorized softmax denominator partials
#pragma unroll
  for (int rb = 0; rb < 2; ++rb) {
    lacc[rb] = f32x4{0.f, 0.f, 0.f, 0.f};
#pragma unroll
    for (int mb = 0; mb < 4; ++mb) Oacc[rb][mb] = f32x4{0.f, 0.f, 0.f, 0.f};
  }

  // prologue: stage tiles 0 and 1, load mask tile 0, publish, prefetch fK(0)
  stageTo(0, 0);
  stageTo(1, 16384);
  float4 mkA[4], mkB[4];
#pragma unroll
  for (int mb = 0; mb < 4; ++mb) mkA[mb] = *(const float4*)(mbase + mb*16);
  __syncthreads();

  bf16x8 fKa[8], fKb[8];
  {
    const char* pA = kvb + laneA;
    const char* pB = kvb + laneB;
#pragma unroll
    for (int mb = 0; mb < 4; ++mb) {
      fKa[mb*2+0] = *(const bf16x8*)(pA + mb*2048);
      fKa[mb*2+1] = *(const bf16x8*)(pB + mb*2048);
    }
  }

  int kvcur = 0, kvnxt = 16384, kvnn = 32768;

  for (int tt = 0; tt < nt2; tt += 2) {
    ATTN_BODY(tt,     fKa, fKb, mkA, mkB);
    ATTN_BODY(tt + 1, fKb, fKa, mkB, mkA);
  }

  // final l reduction across quads (once), then normalize + store O^T
#pragma unroll
  for (int rb = 0; rb < 2; ++rb) {
    float l_ = lacc[rb][0] + lacc[rb][1] + lacc[rb][2] + lacc[rb][3];
    l_ += __shfl_xor(l_, 16);
    l_ += __shfl_xor(l_, 32);
    const float inv = 1.0f / l_;
#pragma unroll
    for (int mb = 0; mb < 4; ++mb) {
      bf16x4 o = bf16x4{(bf16)(Oacc[rb][mb][0]*inv), (bf16)(Oacc[rb][mb][1]*inv),
                        (bf16)(Oacc[rb][mb][2]*inv), (bf16)(Oacc[rb][mb][3]*inv)};
      *(bf16x4*)(out + ((size_t)b*2048 + q0 + rb*16 + l16)*1024 + h*64 + mb*16 + quad*4) = o;
    }
  }
}

// ---------------------------------------------------------------------------
// 4) output projection: 64x128 tiles, grid (64,8) = 512 blocks = 2/CU.
// ---------------------------------------------------------------------------
__global__ __launch_bounds__(256) void oproj_kernel(
    const bf16* __restrict__ Ain, const bf16* __restrict__ Wob,
    const float* __restrict__ bo, float* __restrict__ out)
{
  __shared__ bf16 As[64 * 64];     // 8 KB
  __shared__ bf16 Bs[128 * 64];    // 16 KB
  const int m0 = blockIdx.x * 64, n0 = blockIdx.y * 128;

  const int tid = threadIdx.x, w = tid >> 6, lane = tid & 63;
  const int quad = lane >> 4, l16 = lane & 15;
  const int sw = l16 & 7;
  const int srow8 = lane >> 3;
  const int scol  = ((lane & 7) ^ srow8) * 8;

  f32x4 acc[4][2];
#pragma unroll
  for (int mt = 0; mt < 4; ++mt)
#pragma unroll
    for (int nt = 0; nt < 2; ++nt)
      acc[mt][nt] = f32x4{0.f, 0.f, 0.f, 0.f};

  for (int k0 = 0; k0 < 1024; k0 += 64) {
#pragma unroll
    for (int c4 = 0; c4 < 6; ++c4) {
      const int c = w * 6 + c4;
      if (c < 8) {
        const int row = c * 8 + srow8;
        gload_lds16(Ain + (size_t)(m0 + row) * 1024 + k0 + scol, As + c * 512);
      } else {
        const int cB = c - 8;
        const int row = cB * 8 + srow8;
        gload_lds16(Wob + (size_t)(n0 + row) * 1024 + k0 + scol, Bs + cB * 512);
      }
    }
    __syncthreads();
#pragma unroll
    for (int kk = 0; kk < 2; ++kk) {
      bf16x8 af[4], bfr[2];
#pragma unroll
      for (int mt = 0; mt < 4; ++mt)
        af[mt] = *(const bf16x8*)(As + (mt*16 + l16) * 64 + ((kk*4 + quad) ^ sw) * 8);
#pragma unroll
      for (int nt = 0; nt < 2; ++nt)
        bfr[nt] = *(const bf16x8*)(Bs + (w*32 + nt*16 + l16) * 64 + ((kk*4 + quad) ^ sw) * 8);
#pragma unroll
      for (int mt = 0; mt < 4; ++mt)
#pragma unroll
        for (int nt = 0; nt < 2; ++nt)
          acc[mt][nt] = MFMA_BF16(af[mt], bfr[nt], acc[mt][nt]);
    }
    __syncthreads();
  }

#pragma unroll
  for (int mt = 0; mt < 4; ++mt) {
#pragma unroll
    for (int nt = 0; nt < 2; ++nt) {
      const int n = n0 + w*32 + nt*16 + l16;
      const float bn = bo[n];
#pragma unroll
      for (int r = 0; r < 4; ++r) {
        const int m = m0 + mt*16 + quad*4 + r;
        out[(size_t)m * 1024 + n] = acc[mt][nt][r] + bn;
      }
    }
  }
}

// ---------------------------------------------------------------------------
extern "C" void kernel_launch(void* const* d_in, const int* in_sizes, int n_in,
                              void* d_out, int out_size, void* d_ws, size_t ws_size,
                              hipStream_t stream)
{
  const float* q    = (const float*)d_in[0];
  const float* k    = (const float*)d_in[1];
  const float* v    = (const float*)d_in[2];
  const int*   mask = (const int*)d_in[3];
  const float* Wq   = (const float*)d_in[4];
  const float* bq   = (const float*)d_in[5];
  const float* Wk   = (const float*)d_in[6];
  const float* bk   = (const float*)d_in[7];
  const float* Wv   = (const float*)d_in[8];
  const float* bv   = (const float*)d_in[9];
  const float* Wo   = (const float*)d_in[10];
  const float* bo   = (const float*)d_in[11];

  char* ws = (char*)d_ws;
  bf16*  qb    = (bf16*)(ws);
  bf16*  kb    = (bf16*)(ws + (8ull  << 20));
  bf16*  vb    = (bf16*)(ws + (16ull << 20));
  bf16*  Wqb   = (bf16*)(ws + (24ull << 20));
  bf16*  Wkb   = (bf16*)(ws + (26ull << 20));
  bf16*  Wvb   = (bf16*)(ws + (28ull << 20));
  bf16*  Wob   = (bf16*)(ws + (30ull << 20));
  float* maskc = (float*)(ws + (32ull << 20));
  int*   pref  = (int*)(ws + (32ull << 20) + (64ull << 10));
  int*   cnt   = (int*)(ws + (32ull << 20) + (128ull << 10));
  bf16*  qh    = (bf16*)(ws + (33ull << 20));
  bf16*  kh    = (bf16*)(ws + (41ull << 20));
  bf16*  vhT   = (bf16*)(ws + (49ull << 20));
  bf16*  ao    = (bf16*)(ws);                    // reuse qb region
  float* out   = (float*)d_out;

  scan_kernel<<<2, 256, 0, stream>>>(mask, pref, cnt, maskc, kh, vhT);
  prep_kernel<<<8192, 256, 0, stream>>>(q, k, v, Wq, Wk, Wv, Wo,
                                        qb, kb, vb, Wqb, Wkb, Wvb, Wob);
  proj3_kernel<<<768, 256, 0, stream>>>(qb, kb, vb, Wqb, Wkb, Wvb,
                                        bq, bk, bv, pref, qh, kh, vhT);
  attn_kernel<<<512, 256, 0, stream>>>(qh, kh, vhT, maskc, cnt, ao);
  oproj_kernel<<<dim3(64, 8), 256, 0, stream>>>(ao, Wob, bo, out);
}

// Round 10
// 212.309 us; speedup vs baseline: 1.0754x; 1.0754x over previous
//
#include <hip/hip_runtime.h>
#include <cstdint>
#include <cstddef>

// ---------------------------------------------------------------------------
// MHA forward, bf16 MFMA pipeline, masked-key compaction.
// B=2, S=2048, D=1024, H=16, dk=64. mask is per (batch,key): ~50% of keys are
// dead for ALL heads/queries -> compact K/V to valid keys; attn iterates only
// ceil(cnt/128)*2 tiles (~18 vs 32).
//   0a) scan:    per-batch prefix over mask -> pref[], cnt[]; compacted
//                additive mask (log2 domain). 2 blocks, tiny.
//   0b) zeropad: 64 blocks zero kh pad rows / vhT pad cols [cnt, nt2*64)
//                (NaN guard vs ws poison) -- parallelized (was 2-block serial,
//                ~30us in R13).
//   1) prep:    cast q,k,v,W* fp32->bf16
//   2) proj3:   128x128 tiles, 768 blocks = 3/CU; kh/vhT stores compacted
//   3) attn:    R6 skeleton + compaction, P->PV via per-wave LDS round-trip
//               (permlane asm retired: corrupts under shifted codegen).
//   4) oproj:   64x128 tiles (2 blocks/CU), out = ao@Wo^T + bo (fp32)
// ---------------------------------------------------------------------------

using bf16   = __bf16;
using bf16x4 = __attribute__((ext_vector_type(4))) __bf16;
using bf16x8 = __attribute__((ext_vector_type(8))) __bf16;
using f32x4  = __attribute__((ext_vector_type(4))) float;

#define MFMA_BF16(a, b, c) __builtin_amdgcn_mfma_f32_16x16x32_bf16((a), (b), (c), 0, 0, 0)

__device__ __forceinline__ void gload_lds16(const void* g, void* l) {
  __builtin_amdgcn_global_load_lds((__attribute__((address_space(1))) void*)g,
                                   (__attribute__((address_space(3))) void*)l,
                                   16, 0, 0);
}

#define LOG2E 1.4426950408889634f

// ---------------------------------------------------------------------------
// 0a) scan: one block per batch. Block-scan mask -> pref, cnt, maskc.
// ---------------------------------------------------------------------------
__global__ __launch_bounds__(256) void scan_kernel(
    const int* __restrict__ mask,   // [2][2048]
    int* __restrict__ pref,         // [4096]: dest slot or -1
    int* __restrict__ cnt,          // [2]
    float* __restrict__ maskc)      // [2][2048] additive, log2 domain
{
  const int b = blockIdx.x;
  const int tid = threadIdx.x;
  __shared__ int sums[256];

  const int base = b * 2048 + tid * 8;
  int v[8]; int s_ = 0;
#pragma unroll
  for (int j = 0; j < 8; ++j) { v[j] = (mask[base + j] != 0) ? 1 : 0; s_ += v[j]; }
  sums[tid] = s_;
  __syncthreads();
  for (int off = 1; off < 256; off <<= 1) {
    int x = sums[tid];
    int y = (tid >= off) ? sums[tid - off] : 0;
    __syncthreads();
    sums[tid] = x + y;
    __syncthreads();
  }
  const int excl  = tid ? sums[tid - 1] : 0;
  const int total = sums[255];
  int run = excl;
#pragma unroll
  for (int j = 0; j < 8; ++j) { pref[base + j] = v[j] ? run : -1; run += v[j]; }
  if (tid == 0) cnt[b] = total;

  // compacted additive mask: 0 for valid slots, -inf (log2) for the rest
  for (int sc = tid; sc < 2048; sc += 256)
    maskc[b * 2048 + sc] = (sc < total) ? 0.0f : -1e9f * LOG2E;
}

// ---------------------------------------------------------------------------
// 0b) zeropad: 64 blocks = (b, h, half). Zero kh pad rows / vhT pad cols in
//     [cnt[b], nt2*64). Disjoint from proj3's valid-slot writes.
// ---------------------------------------------------------------------------
__global__ __launch_bounds__(256) void zeropad_kernel(
    const int* __restrict__ cnt, bf16* __restrict__ kh, bf16* __restrict__ vhT)
{
  const int z = blockIdx.x;
  const int b = z >> 5, h = (z >> 1) & 15, half = z & 1;
  const int tid = threadIdx.x;
  const int total = cnt[b];
  int nt2 = ((total + 127) >> 7) * 2;
  if (nt2 < 2) nt2 = 2;
  const int span = nt2 * 64;          // multiple of 128, <= 2048
  const int npad = span - total;      // 0..128

  const bf16x8 z8 = bf16x8{(bf16)0.f,(bf16)0.f,(bf16)0.f,(bf16)0.f,
                           (bf16)0.f,(bf16)0.f,(bf16)0.f,(bf16)0.f};
  if (half == 0) {
    // kh pad rows: npad rows x 64 d, bf16x8 chunks (rows 64-elem aligned)
    for (int c = tid; c < npad * 8; c += 256) {
      const int ro = c >> 3, dd = (c & 7) * 8;
      *(bf16x8*)(kh + (((size_t)(b*16 + h) * 2048 + total + ro) * 64 + dd)) = z8;
    }
  } else {
    // vhT pad cols: 64 d-rows x npad cols (scalar; start col unaligned)
    bf16* base = vhT + ((size_t)(b*16 + h) * 64) * 2048 + total;
    for (int d = 0; d < 64; ++d) {
      bf16* p = base + (size_t)d * 2048;
      for (int co = tid; co < npad; co += 256) p[co] = (bf16)0.f;
    }
  }
}

// ---------------------------------------------------------------------------
// 1) prep — 2 elements per thread, grid 8192 (exactly 3*NQ+4*NW float4s)
// ---------------------------------------------------------------------------
__global__ __launch_bounds__(256) void prep_kernel(
    const float* __restrict__ q, const float* __restrict__ k, const float* __restrict__ v,
    const float* __restrict__ Wq, const float* __restrict__ Wk,
    const float* __restrict__ Wv, const float* __restrict__ Wo,
    bf16* __restrict__ qb, bf16* __restrict__ kb, bf16* __restrict__ vb,
    bf16* __restrict__ Wqb, bf16* __restrict__ Wkb, bf16* __restrict__ Wvb,
    bf16* __restrict__ Wob)
{
  const int NQ = 1048576;
  const int NW = 262144;
  const int STRIDE = 8192 * 256;
#pragma unroll
  for (int s = 0; s < 2; ++s) {
    int i = blockIdx.x * 256 + threadIdx.x + s * STRIDE;
    if (i < 3 * NQ) {
      const float* src; bf16* dst; int j;
      if (i < NQ)        { src = q; dst = qb; j = i; }
      else if (i < 2*NQ) { src = k; dst = kb; j = i - NQ; }
      else               { src = v; dst = vb; j = i - 2*NQ; }
      float4 f = ((const float4*)src)[j];
      ((bf16x4*)dst)[j] = bf16x4{(bf16)f.x, (bf16)f.y, (bf16)f.z, (bf16)f.w};
    } else {
      int j = i - 3*NQ;
      const float* src; bf16* dst;
      if (j < NW)        { src = Wq; dst = Wqb; }
      else if (j < 2*NW) { src = Wk; dst = Wkb; j -= NW; }
      else if (j < 3*NW) { src = Wv; dst = Wvb; j -= 2*NW; }
      else               { src = Wo; dst = Wob; j -= 3*NW; }
      float4 f = ((const float4*)src)[j];
      ((bf16x4*)dst)[j] = bf16x4{(bf16)f.x, (bf16)f.y, (bf16)f.z, (bf16)f.w};
    }
  }
}

// ---------------------------------------------------------------------------
// 2) fused QKV projections, 128x128 tiles, grid 768 = 3 blocks/CU exactly.
//    kh rows and vhT cols stored at compacted slot pref[token] (skip masked).
// ---------------------------------------------------------------------------
__global__ __launch_bounds__(256, 3) void proj3_kernel(
    const bf16* __restrict__ Xq, const bf16* __restrict__ Xk, const bf16* __restrict__ Xv,
    const bf16* __restrict__ Wqb, const bf16* __restrict__ Wkb, const bf16* __restrict__ Wvb,
    const float* __restrict__ bq, const float* __restrict__ bk, const float* __restrict__ bv,
    const int* __restrict__ pref,
    bf16* __restrict__ qh, bf16* __restrict__ kh, bf16* __restrict__ vhT)
{
  __shared__ bf16 As[128 * 64];   // 16 KB
  __shared__ bf16 Bs[128 * 64];   // 16 KB

  const int bid = blockIdx.x;
  const int z   = bid >> 8;        // 0,1,2
  const int r_  = bid & 255;

  const int tid = threadIdx.x, w = tid >> 6, lane = tid & 63;
  const int wr = w >> 1, wc = w & 1;
  const int quad = lane >> 4, l16 = lane & 15;
  const int sw = l16 & 7;
  const int srow8 = lane >> 3;
  const int scol  = ((lane & 7) ^ srow8) * 8;

  const bf16* Aptr; const bf16* Bptr;
  int m0, n0;
  if (z == 2) { Aptr = Wvb; Bptr = Xv; m0 = (r_ >> 5) * 128; n0 = (r_ & 31) * 128; }
  else        { Aptr = (z == 0) ? Xq : Xk; Bptr = (z == 0) ? Wqb : Wkb;
                m0 = (r_ >> 3) * 128; n0 = (r_ & 7) * 128; }

  f32x4 acc[4][4];
#pragma unroll
  for (int mt = 0; mt < 4; ++mt)
#pragma unroll
    for (int nt = 0; nt < 4; ++nt)
      acc[mt][nt] = f32x4{0.f, 0.f, 0.f, 0.f};

  for (int k0 = 0; k0 < 1024; k0 += 64) {
#pragma unroll
    for (int c8 = 0; c8 < 8; ++c8) {
      const int c = w * 8 + c8;
      if (c < 16) {
        const int row = c * 8 + srow8;
        gload_lds16(Aptr + (size_t)(m0 + row) * 1024 + k0 + scol, As + c * 512);
      } else {
        const int cB = c - 16;
        const int row = cB * 8 + srow8;
        gload_lds16(Bptr + (size_t)(n0 + row) * 1024 + k0 + scol, Bs + cB * 512);
      }
    }
    __syncthreads();
#pragma unroll
    for (int kk = 0; kk < 2; ++kk) {
      bf16x8 af[4], bf[4];
#pragma unroll
      for (int mt = 0; mt < 4; ++mt)
        af[mt] = *(const bf16x8*)(As + (wr*64 + mt*16 + l16) * 64 + ((kk*4 + quad) ^ sw) * 8);
#pragma unroll
      for (int nt = 0; nt < 4; ++nt)
        bf[nt] = *(const bf16x8*)(Bs + (wc*64 + nt*16 + l16) * 64 + ((kk*4 + quad) ^ sw) * 8);
#pragma unroll
      for (int mt = 0; mt < 4; ++mt)
#pragma unroll
        for (int nt = 0; nt < 4; ++nt)
          acc[mt][nt] = MFMA_BF16(af[mt], bf[nt], acc[mt][nt]);
    }
    __syncthreads();
  }

  if (z == 2) {
    // C rows = Wv-row dv, cols = token; store vhT[bh][d][sc] compacted
    int sc4[4];
#pragma unroll
    for (int nt = 0; nt < 4; ++nt)
      sc4[nt] = pref[n0 + wc*64 + nt*16 + l16];
#pragma unroll
    for (int mt = 0; mt < 4; ++mt) {
      const int dvb = m0 + wr*64 + mt*16 + quad*4;
      const float4 bv4 = *(const float4*)(bv + dvb);
#pragma unroll
      for (int nt = 0; nt < 4; ++nt) {
        const int tok = n0 + wc*64 + nt*16 + l16;
        const int bb = tok >> 11;
        if (sc4[nt] >= 0) {
#pragma unroll
          for (int r = 0; r < 4; ++r) {
            const int dv = dvb + r;
            const int h = dv >> 6, d = dv & 63;
            vhT[(((size_t)bb*16 + h)*64 + d)*2048 + sc4[nt]] = (bf16)(acc[mt][nt][r] + (&bv4.x)[r]);
          }
        }
      }
    }
  } else if (z == 0) {
#pragma unroll
    for (int mt = 0; mt < 4; ++mt) {
#pragma unroll
      for (int nt = 0; nt < 4; ++nt) {
        const int n = n0 + wc*64 + nt*16 + l16;
        const int h = n >> 6, d = n & 63;
        const float bn = bq[n];
#pragma unroll
        for (int r = 0; r < 4; ++r) {
          const int m  = m0 + wr*64 + mt*16 + quad*4 + r;
          const int bb = m >> 11, s = m & 2047;
          const float val = acc[mt][nt][r] + bn;
          qh[(((size_t)bb*16 + h)*2048 + s)*64 + d] = (bf16)(val * (0.125f * LOG2E));
        }
      }
    }
  } else {
#pragma unroll
    for (int mt = 0; mt < 4; ++mt) {
      int dst4[4];
#pragma unroll
      for (int r = 0; r < 4; ++r)
        dst4[r] = pref[m0 + wr*64 + mt*16 + quad*4 + r];
#pragma unroll
      for (int nt = 0; nt < 4; ++nt) {
        const int n = n0 + wc*64 + nt*16 + l16;
        const int h = n >> 6, d = n & 63;
        const float bn = bk[n];
#pragma unroll
        for (int r = 0; r < 4; ++r) {
          const int bb = (m0 + wr*64 + mt*16 + quad*4 + r) >> 11;
          if (dst4[r] >= 0) {
            const float val = acc[mt][nt][r] + bn;
            kh[(((size_t)bb*16 + h)*2048 + dst4[r])*64 + d] = (bf16)val;
          }
        }
      }
    }
  }
}

// ---------------------------------------------------------------------------
// 3) flash attention (R6 skeleton + compaction, LDS P round-trip): 256-thr
// blocks (4 waves, 128 q-rows), grid 512 = 2 blocks/CU; triple-buffered K/V
// LDS; K-fragments register-prefetched one tile ahead; P->PV via per-wave
// LDS staging (proven, no inline asm). Dynamic EVEN tile count
// nt2 = 2*ceil(cnt[b]/128). 1 barrier/tile. bh=(L&7)+8*(L>>7).
// ---------------------------------------------------------------------------
#define PSTRIDE 72   // P staging row stride (64+8): banks rotate, 16B aligned

#define ATTN_BODY(T, FKC, FKN, MKC, MKN)                                        \
  {                                                                             \
    if ((T) + 2 < nt2) stageTo((T) + 2, kvnn);                                  \
    if ((T) + 1 < nt2) {                                                        \
      _Pragma("unroll")                                                         \
      for (int mb = 0; mb < 4; ++mb)                                            \
        MKN[mb] = *(const float4*)(mbase + ((T) + 1) * 64 + mb * 16);           \
      const char* pA = kvb + kvnxt + laneA;                                     \
      const char* pB = kvb + kvnxt + laneB;                                     \
      _Pragma("unroll")                                                         \
      for (int mb = 0; mb < 4; ++mb) {                                          \
        FKN[mb*2+0] = *(const bf16x8*)(pA + mb*2048);                           \
        FKN[mb*2+1] = *(const bf16x8*)(pB + mb*2048);                           \
      }                                                                         \
    }                                                                           \
    bf16x8 fV[8];                                                               \
    {                                                                           \
      const char* pA = kvb + kvcur + 8192 + laneA;                              \
      const char* pB = kvb + kvcur + 8192 + laneB;                              \
      _Pragma("unroll")                                                         \
      for (int mb = 0; mb < 4; ++mb) {                                          \
        fV[mb*2+0] = *(const bf16x8*)(pA + mb*2048);                            \
        fV[mb*2+1] = *(const bf16x8*)(pB + mb*2048);                            \
      }                                                                         \
    }                                                                           \
    _Pragma("unroll")                                                           \
    for (int rb = 0; rb < 2; ++rb) {                                            \
      f32x4 sac[4];                                                             \
      _Pragma("unroll")                                                         \
      for (int mb = 0; mb < 4; ++mb)                                            \
        sac[mb] = f32x4{MKC[mb].x, MKC[mb].y, MKC[mb].z, MKC[mb].w};            \
      _Pragma("unroll")                                                         \
      for (int kk = 0; kk < 2; ++kk)                                            \
        _Pragma("unroll")                                                       \
        for (int mb = 0; mb < 4; ++mb)                                          \
          sac[mb] = MFMA_BF16(FKC[mb*2+kk], aQ[rb][kk], sac[mb]);               \
      float p[4][4];                                                            \
      _Pragma("unroll")                                                         \
      for (int mb = 0; mb < 4; ++mb) {                                          \
        _Pragma("unroll")                                                       \
        for (int r = 0; r < 4; ++r) p[mb][r] = __builtin_amdgcn_exp2f(sac[mb][r]); \
        lacc[rb] += f32x4{p[mb][0], p[mb][1], p[mb][2], p[mb][3]};              \
      }                                                                         \
      _Pragma("unroll")                                                         \
      for (int mb = 0; mb < 4; ++mb) {                                          \
        bf16x4 pk = bf16x4{(bf16)p[mb][0], (bf16)p[mb][1],                      \
                           (bf16)p[mb][2], (bf16)p[mb][3]};                     \
        *(bf16x4*)(bW + mb*16) = pk;                                            \
      }                                                                         \
      _Pragma("unroll")                                                         \
      for (int kk = 0; kk < 2; ++kk) {                                          \
        bf16x8 aP = *(const bf16x8*)(bR + kk*32);                               \
        _Pragma("unroll")                                                       \
        for (int mb = 0; mb < 4; ++mb)                                          \
          Oacc[rb][mb] = MFMA_BF16(fV[mb*2+kk], aP, Oacc[rb][mb]);              \
      }                                                                         \
    }                                                                           \
    __syncthreads();                                                            \
    { int tmp_ = kvcur; kvcur = kvnxt; kvnxt = kvnn; kvnn = tmp_; }             \
  }

__global__ __launch_bounds__(256, 2) void attn_kernel(
    const bf16* __restrict__ qh, const bf16* __restrict__ kh,
    const bf16* __restrict__ vhT, const float* __restrict__ maskc,
    const int* __restrict__ cnt, bf16* __restrict__ out)
{
  __shared__ bf16 KV[3][2][4096];       // [buf][K|V][64*64], 48 KB, XOR-swz
  __shared__ bf16 Ps[4][16 * PSTRIDE];  // per-wave P staging, 9 KB

  const int tid = threadIdx.x, w = tid >> 6, lane = tid & 63;
  const int quad = lane >> 4, l16 = lane & 15;
  const int sw = l16 & 7;
  const int srow8 = lane >> 3;
  const int scol  = ((lane & 7) ^ srow8) * 8;

  const int L  = blockIdx.x;
  const int bh = (L & 7) + ((L >> 7) << 3);
  const int qt = (L >> 3) & 15;
  const int b  = bh >> 4, h = bh & 15;
  const int q0 = qt * 128 + w * 32;

  const bf16* kbase = kh  + (size_t)bh * 2048 * 64;
  const bf16* vbase = vhT + (size_t)bh * 64 * 2048;
  const bf16* qbase = qh  + ((size_t)bh * 2048 + q0) * 64;
  const float* mbase = maskc + (size_t)b * 2048 + quad * 4;

  // dynamic even tile count from compacted key count
  const int total = cnt[b];
  int nt2 = ((total + 127) >> 7) * 2;
  if (nt2 < 2) nt2 = 2;

  char* kvb = (char*)&KV[0][0][0];
  bf16* Pw = Ps[w];

  auto stageTo = [&](int t, int bufoff) {
    const int kt0 = t * 64;
#pragma unroll
    for (int c2 = 0; c2 < 2; ++c2) {
      const int c   = w * 2 + c2;        // chunk 0..7, 1KB each
      const int row = c * 8 + srow8;
      gload_lds16(kbase + (size_t)(kt0 + row) * 64 + scol, kvb + bufoff + c * 1024);
      gload_lds16(vbase + (size_t)row * 2048 + kt0 + scol, kvb + bufoff + 8192 + c * 1024);
    }
  };

  // Q fragments (B-operand for S^T = K.Q^T)
  bf16x8 aQ[2][2];
#pragma unroll
  for (int rb = 0; rb < 2; ++rb)
#pragma unroll
    for (int kk = 0; kk < 2; ++kk)
      aQ[rb][kk] = *(const bf16x8*)(qbase + (size_t)(rb*16 + l16)*64 + kk*32 + quad*8);

  // loop-invariant LDS addressing (all ds ops get immediate offsets)
  const int laneA = l16 * 128 + ((quad    ) ^ sw) * 16;   // kk=0 slot
  const int laneB = l16 * 128 + ((quad + 4) ^ sw) * 16;   // kk=1 slot
  bf16*       bW = Pw + l16 * PSTRIDE + quad * 4;
  const bf16* bR = Pw + l16 * PSTRIDE + quad * 8;

  f32x4 Oacc[2][4];            // O^T: row d = mb*16+quad*4+r, col q = l16
  f32x4 lacc[2];               // vectorized softmax denominator partials
#pragma unroll
  for (int rb = 0; rb < 2; ++rb) {
    lacc[rb] = f32x4{0.f, 0.f, 0.f, 0.f};
#pragma unroll
    for (int mb = 0; mb < 4; ++mb) Oacc[rb][mb] = f32x4{0.f, 0.f, 0.f, 0.f};
  }

  // prologue: stage tiles 0 and 1, load mask tile 0, publish, prefetch fK(0)
  stageTo(0, 0);
  stageTo(1, 16384);
  float4 mkA[4], mkB[4];
#pragma unroll
  for (int mb = 0; mb < 4; ++mb) mkA[mb] = *(const float4*)(mbase + mb*16);
  __syncthreads();

  bf16x8 fKa[8], fKb[8];
  {
    const char* pA = kvb + laneA;
    const char* pB = kvb + laneB;
#pragma unroll
    for (int mb = 0; mb < 4; ++mb) {
      fKa[mb*2+0] = *(const bf16x8*)(pA + mb*2048);
      fKa[mb*2+1] = *(const bf16x8*)(pB + mb*2048);
    }
  }

  int kvcur = 0, kvnxt = 16384, kvnn = 32768;

  for (int tt = 0; tt < nt2; tt += 2) {
    ATTN_BODY(tt,     fKa, fKb, mkA, mkB);
    ATTN_BODY(tt + 1, fKb, fKa, mkB, mkA);
  }

  // final l reduction across quads (once), then normalize + store O^T
#pragma unroll
  for (int rb = 0; rb < 2; ++rb) {
    float l_ = lacc[rb][0] + lacc[rb][1] + lacc[rb][2] + lacc[rb][3];
    l_ += __shfl_xor(l_, 16);
    l_ += __shfl_xor(l_, 32);
    const float inv = 1.0f / l_;
#pragma unroll
    for (int mb = 0; mb < 4; ++mb) {
      bf16x4 o = bf16x4{(bf16)(Oacc[rb][mb][0]*inv), (bf16)(Oacc[rb][mb][1]*inv),
                        (bf16)(Oacc[rb][mb][2]*inv), (bf16)(Oacc[rb][mb][3]*inv)};
      *(bf16x4*)(out + ((size_t)b*2048 + q0 + rb*16 + l16)*1024 + h*64 + mb*16 + quad*4) = o;
    }
  }
}

// ---------------------------------------------------------------------------
// 4) output projection: 64x128 tiles, grid (64,8) = 512 blocks = 2/CU.
// ---------------------------------------------------------------------------
__global__ __launch_bounds__(256) void oproj_kernel(
    const bf16* __restrict__ Ain, const bf16* __restrict__ Wob,
    const float* __restrict__ bo, float* __restrict__ out)
{
  __shared__ bf16 As[64 * 64];     // 8 KB
  __shared__ bf16 Bs[128 * 64];    // 16 KB
  const int m0 = blockIdx.x * 64, n0 = blockIdx.y * 128;

  const int tid = threadIdx.x, w = tid >> 6, lane = tid & 63;
  const int quad = lane >> 4, l16 = lane & 15;
  const int sw = l16 & 7;
  const int srow8 = lane >> 3;
  const int scol  = ((lane & 7) ^ srow8) * 8;

  f32x4 acc[4][2];
#pragma unroll
  for (int mt = 0; mt < 4; ++mt)
#pragma unroll
    for (int nt = 0; nt < 2; ++nt)
      acc[mt][nt] = f32x4{0.f, 0.f, 0.f, 0.f};

  for (int k0 = 0; k0 < 1024; k0 += 64) {
#pragma unroll
    for (int c4 = 0; c4 < 6; ++c4) {
      const int c = w * 6 + c4;
      if (c < 8) {
        const int row = c * 8 + srow8;
        gload_lds16(Ain + (size_t)(m0 + row) * 1024 + k0 + scol, As + c * 512);
      } else {
        const int cB = c - 8;
        const int row = cB * 8 + srow8;
        gload_lds16(Wob + (size_t)(n0 + row) * 1024 + k0 + scol, Bs + cB * 512);
      }
    }
    __syncthreads();
#pragma unroll
    for (int kk = 0; kk < 2; ++kk) {
      bf16x8 af[4], bfr[2];
#pragma unroll
      for (int mt = 0; mt < 4; ++mt)
        af[mt] = *(const bf16x8*)(As + (mt*16 + l16) * 64 + ((kk*4 + quad) ^ sw) * 8);
#pragma unroll
      for (int nt = 0; nt < 2; ++nt)
        bfr[nt] = *(const bf16x8*)(Bs + (w*32 + nt*16 + l16) * 64 + ((kk*4 + quad) ^ sw) * 8);
#pragma unroll
      for (int mt = 0; mt < 4; ++mt)
#pragma unroll
        for (int nt = 0; nt < 2; ++nt)
          acc[mt][nt] = MFMA_BF16(af[mt], bfr[nt], acc[mt][nt]);
    }
    __syncthreads();
  }

#pragma unroll
  for (int mt = 0; mt < 4; ++mt) {
#pragma unroll
    for (int nt = 0; nt < 2; ++nt) {
      const int n = n0 + w*32 + nt*16 + l16;
      const float bn = bo[n];
#pragma unroll
      for (int r = 0; r < 4; ++r) {
        const int m = m0 + mt*16 + quad*4 + r;
        out[(size_t)m * 1024 + n] = acc[mt][nt][r] + bn;
      }
    }
  }
}

// ---------------------------------------------------------------------------
extern "C" void kernel_launch(void* const* d_in, const int* in_sizes, int n_in,
                              void* d_out, int out_size, void* d_ws, size_t ws_size,
                              hipStream_t stream)
{
  const float* q    = (const float*)d_in[0];
  const float* k    = (const float*)d_in[1];
  const float* v    = (const float*)d_in[2];
  const int*   mask = (const int*)d_in[3];
  const float* Wq   = (const float*)d_in[4];
  const float* bq   = (const float*)d_in[5];
  const float* Wk   = (const float*)d_in[6];
  const float* bk   = (const float*)d_in[7];
  const float* Wv   = (const float*)d_in[8];
  const float* bv   = (const float*)d_in[9];
  const float* Wo   = (const float*)d_in[10];
  const float* bo   = (const float*)d_in[11];

  char* ws = (char*)d_ws;
  bf16*  qb    = (bf16*)(ws);
  bf16*  kb    = (bf16*)(ws + (8ull  << 20));
  bf16*  vb    = (bf16*)(ws + (16ull << 20));
  bf16*  Wqb   = (bf16*)(ws + (24ull << 20));
  bf16*  Wkb   = (bf16*)(ws + (26ull << 20));
  bf16*  Wvb   = (bf16*)(ws + (28ull << 20));
  bf16*  Wob   = (bf16*)(ws + (30ull << 20));
  float* maskc = (float*)(ws + (32ull << 20));
  int*   pref  = (int*)(ws + (32ull << 20) + (64ull << 10));
  int*   cnt   = (int*)(ws + (32ull << 20) + (128ull << 10));
  bf16*  qh    = (bf16*)(ws + (33ull << 20));
  bf16*  kh    = (bf16*)(ws + (41ull << 20));
  bf16*  vhT   = (bf16*)(ws + (49ull << 20));
  bf16*  ao    = (bf16*)(ws);                    // reuse qb region
  float* out   = (float*)d_out;

  scan_kernel<<<2, 256, 0, stream>>>(mask, pref, cnt, maskc);
  zeropad_kernel<<<64, 256, 0, stream>>>(cnt, kh, vhT);
  prep_kernel<<<8192, 256, 0, stream>>>(q, k, v, Wq, Wk, Wv, Wo,
                                        qb, kb, vb, Wqb, Wkb, Wvb, Wob);
  proj3_kernel<<<768, 256, 0, stream>>>(qb, kb, vb, Wqb, Wkb, Wvb,
                                        bq, bk, bv, pref, qh, kh, vhT);
  attn_kernel<<<512, 256, 0, stream>>>(qh, kh, vhT, maskc, cnt, ao);
  oproj_kernel<<<dim3(64, 8), 256, 0, stream>>>(ao, Wob, bo, out);
}